// Round 7
// baseline (76.085 us; speedup 1.0000x reference)
//
#include <hip/hip_runtime.h>
#include <stdint.h>
#include <math.h>

constexpr int NPG = 32768;
constexpr int NGRAPH = 128;
constexpr int L1 = 5, L2 = 64, L3 = 32, L4 = 8;
constexpr int K1 = 328, K2 = 33, K3 = 4;
constexpr int SEGS = 4;                    // score blocks per graph
constexpr int NGRP_SEG = NPG / SEGS / 4;   // 2048 groups-of-4 per segment

__device__ __forceinline__ uint32_t mono(float f) {
  uint32_t u = __float_as_uint(f);
  return (u & 0x80000000u) ? ~u : (u | 0x80000000u);
}
__device__ __forceinline__ float imono(uint32_t k) {
  uint32_t u = (k & 0x80000000u) ? (k ^ 0x80000000u) : ~k;
  return __uint_as_float(u);
}

// wave-0: pick threshold bucket from nb-bin histogram (suffix scan from top).
__device__ __forceinline__ void pick_bucket(const uint32_t* hist, int nb, int bits,
                                            uint32_t* s_prefix, int* s_rem,
                                            int* s_nc, int tid) {
  if (tid < 64) {
    const int chunk = (nb >= 64) ? (nb >> 6) : 1;
    const int nlane = (nb >= 64) ? 64 : nb;
    const int base = tid * chunk;
    uint32_t S = 0;
    if (tid < nlane)
      for (int b = 0; b < chunk; ++b) S += hist[base + b];
    uint32_t incl = S;
    for (int d = 1; d < 64; d <<= 1) {
      uint32_t t = __shfl_down(incl, d);
      if (tid + d < 64) incl += t;
    }
    uint32_t above = incl - S;
    uint32_t rem = (uint32_t)*s_rem;
    if (tid < nlane && above < rem && rem <= incl) {  // exactly one winner
      uint32_t cum = above;
      for (int b = chunk - 1; b >= 0; --b) {
        uint32_t h = hist[base + b];
        if (cum + h >= rem) {
          int rnew = (int)(rem - cum);
          *s_rem = rnew;
          *s_nc = (K1 - rnew) + (int)h;
          *s_prefix = (*s_prefix << bits) | (uint32_t)(base + b);
          break;
        }
        cum += h;
      }
    }
  }
}

// ---- kernel 1: score 8192 nodes, write key16 + per-block histogram ----
// 512 blocks x 1024 threads; LDS = 8 KB -> multiple blocks/CU, full GPU.
__global__ __launch_bounds__(1024) void score_hist_kernel(
    const float* __restrict__ x, const float* __restrict__ w1,
    uint16_t* __restrict__ key16, uint32_t* __restrict__ histg) {
  __shared__ uint32_t hist[2048];
  const int tid = threadIdx.x;
  hist[tid] = 0;
  hist[tid + 1024] = 0;
  const int g = blockIdx.x >> 2;
  const int seg = blockIdx.x & 3;
  const float* xg = x + (size_t)g * NPG * L1;
  const float w10 = w1[0], w11 = w1[1], w12 = w1[2], w13 = w1[3], w14 = w1[4];
  __syncthreads();
  uint2* kg = (uint2*)(key16 + (size_t)g * NPG);
#pragma unroll
  for (int q = 0; q < 2; ++q) {
    const int G = seg * NGRP_SEG + tid + 1024 * q;   // group of 4 nodes
    const float4* p = (const float4*)xg + (size_t)G * 5;
    float4 a = p[0], b = p[1], c = p[2], d = p[3], e = p[4];
    uint32_t k0 = mono(a.x*w10 + a.y*w11 + a.z*w12 + a.w*w13 + b.x*w14);
    uint32_t k1 = mono(b.y*w10 + b.z*w11 + b.w*w12 + c.x*w13 + c.y*w14);
    uint32_t k2 = mono(c.z*w10 + c.w*w11 + d.x*w12 + d.y*w13 + d.z*w14);
    uint32_t k3 = mono(d.w*w10 + e.x*w11 + e.y*w12 + e.z*w13 + e.w*w14);
    uint2 pk;
    pk.x = (k0 >> 16) | (k1 & 0xFFFF0000u);
    pk.y = (k2 >> 16) | (k3 & 0xFFFF0000u);
    kg[G] = pk;
    atomicAdd(&hist[k0 >> 21], 1u);                  // top 11 bits == key16 >> 5
    atomicAdd(&hist[k1 >> 21], 1u);
    atomicAdd(&hist[k2 >> 21], 1u);
    atomicAdd(&hist[k3 >> 21], 1u);
  }
  __syncthreads();
  uint32_t* hb = histg + (size_t)blockIdx.x * 2048;
  hb[tid] = hist[tid];
  hb[tid + 1024] = hist[tid + 1024];
}

// ---- kernel 2: per-graph threshold + collect + exact rank + full MLP ----
__global__ __launch_bounds__(1024, 1) void select_mlp_kernel(
    const float* __restrict__ x, const uint16_t* __restrict__ key16,
    const uint32_t* __restrict__ histg,
    const float* __restrict__ w1, const float* __restrict__ W_ih,
    const float* __restrict__ b_ih, const float* __restrict__ b_hh,
    const float* __restrict__ w2, const float* __restrict__ W2,
    const float* __restrict__ b2, const float* __restrict__ w3,
    const float* __restrict__ W3, const float* __restrict__ b3,
    float* __restrict__ out) {
  __shared__ __align__(16) float hbuf[K1 * 65 + K2 * 65 + K2 * 33];  // 98.2 KB
  __shared__ __align__(16) unsigned long long comp[1024];   // 8 KB
  __shared__ __align__(16) unsigned long long sorted[512];  // 4 KB
  __shared__ __align__(16) float fa[4608];                  // 18 KB
  __shared__ uint32_t s_prefix;
  __shared__ int s_rem, s_nc, s_cnt;
  __shared__ float s_inv[3];

  uint32_t* hist = (uint32_t*)hbuf;  // 2048 bins; dead before hbuf is written
  float* xsel = fa;                  // [K1*L1]
  float* sWih = fa + 1640;
  float* sbih = fa + 1960;           // b_ih + b_hh
  float* sW2  = fa + 2024;           // [L3][65]
  float* sb2  = fa + 4104;
  float* sw2v = fa + 4136;
  float* sw3v = fa + 4200;
  float* sW3  = fa + 4232;
  float* sb3  = fa + 4488;

  const int tid = threadIdx.x;
  const int g = blockIdx.x;
  const float* xg = x + (size_t)g * NPG * L1;
  const uint16_t* kg = key16 + (size_t)g * NPG;

  // sum the graph's 4 per-segment histograms
  {
    const uint32_t* h0 = histg + (size_t)(4 * g) * 2048;
    for (int i = tid; i < 2048; i += 1024)
      hist[i] = h0[i] + h0[i + 2048] + h0[i + 4096] + h0[i + 6144];
  }
  for (int i = tid; i < L2 * L1; i += 1024) sWih[i] = W_ih[i];
  for (int i = tid; i < L2; i += 1024) { sbih[i] = b_ih[i] + b_hh[i]; sw2v[i] = w2[i]; }
  for (int i = tid; i < L3 * L2; i += 1024) sW2[(i >> 6) * 65 + (i & 63)] = W2[i];
  for (int i = tid; i < L3; i += 1024) { sb2[i] = b2[i]; sw3v[i] = w3[i]; }
  for (int i = tid; i < L4 * L3; i += 1024) sW3[i] = W3[i];
  for (int i = tid; i < L4; i += 1024) sb3[i] = b3[i];
  if (tid == 0) {
    s_cnt = 0; s_rem = K1; s_nc = 0; s_prefix = 0u;
    float s = 0.f;
    for (int k = 0; k < L1; ++k) s += w1[k] * w1[k];
    s_inv[0] = 1.f / sqrtf(s);
  } else if (tid == 1) {
    float s = 0.f;
    for (int k = 0; k < L2; ++k) s += w2[k] * w2[k];
    s_inv[1] = 1.f / sqrtf(s);
  } else if (tid == 2) {
    float s = 0.f;
    for (int k = 0; k < L3; ++k) s += w3[k] * w3[k];
    s_inv[2] = 1.f / sqrtf(s);
  }
  const float w10 = w1[0], w11 = w1[1], w12 = w1[2], w13 = w1[3], w14 = w1[4];
  __syncthreads();

  // threshold: 11-bit digit, then 5-bit refine if bucket too fat
  pick_bucket(hist, 2048, 11, &s_prefix, &s_rem, &s_nc, tid);
  __syncthreads();
  int consumed = 11;
  if (s_nc > 1024) {
    const uint32_t pref11 = s_prefix;
    __syncthreads();
    if (tid < 32) hist[tid] = 0;
    __syncthreads();
#pragma unroll
    for (int q = 0; q < 8; ++q) {
      uint2 pk = ((const uint2*)kg)[tid + 1024 * q];
      uint32_t h0 = pk.x & 0xFFFFu, h1 = pk.x >> 16;
      uint32_t h2 = pk.y & 0xFFFFu, h3 = pk.y >> 16;
      if ((h0 >> 5) == pref11) atomicAdd(&hist[h0 & 31u], 1u);
      if ((h1 >> 5) == pref11) atomicAdd(&hist[h1 & 31u], 1u);
      if ((h2 >> 5) == pref11) atomicAdd(&hist[h2 & 31u], 1u);
      if ((h3 >> 5) == pref11) atomicAdd(&hist[h3 & 31u], 1u);
    }
    __syncthreads();
    pick_bucket(hist, 32, 5, &s_prefix, &s_rem, &s_nc, tid);
    __syncthreads();
    consumed = 16;
  }
  const uint32_t T16 = s_prefix << (16 - consumed);  // monotone-trunc superset threshold

  // collect candidates; recompute EXACT dot for each
  for (int q = 0; q < 8; ++q) {
    const int g4 = tid + 1024 * q;
    uint2 pk = ((const uint2*)kg)[g4];
    uint32_t h[4] = { pk.x & 0xFFFFu, pk.x >> 16, pk.y & 0xFFFFu, pk.y >> 16 };
#pragma unroll
    for (int j = 0; j < 4; ++j) {
      if (h[j] >= T16) {
        int p = atomicAdd(&s_cnt, 1);
        if (p < 1024) {
          int i = 4 * g4 + j;
          const float* r = xg + (size_t)i * L1;
          float dv = r[0]*w10 + r[1]*w11 + r[2]*w12 + r[3]*w13 + r[4]*w14;
          comp[p] = ((unsigned long long)mono(dv) << 16) | (unsigned)(65535 - i);
        }
      }
    }
  }
  __syncthreads();
  int cnt = s_cnt; if (cnt > 1024) cnt = 1024;
  const int nrk = (cnt <= 512) ? 512 : 1024;
  for (int i = tid; i < nrk; i += 1024)
    if (i >= cnt) comp[i] = 0ULL;
  __syncthreads();
  if (tid < nrk) {   // unrolled broadcast counting-rank
    unsigned long long c = comp[tid];
    int r = 0;
    for (int i = 0; i < nrk; i += 8) {
      ulonglong2 v0 = *(const ulonglong2*)&comp[i];
      ulonglong2 v1 = *(const ulonglong2*)&comp[i + 2];
      ulonglong2 v2 = *(const ulonglong2*)&comp[i + 4];
      ulonglong2 v3 = *(const ulonglong2*)&comp[i + 6];
      r += (v0.x > c) + (v0.y > c) + (v1.x > c) + (v1.y > c) +
           (v2.x > c) + (v2.y > c) + (v3.x > c) + (v3.y > c);
    }
    if (r < K1) sorted[r] = c;
  }
  __syncthreads();

  const float inv1 = s_inv[0], inv2 = s_inv[1], inv3 = s_inv[2];

  // phase E: gather x rows * score1 (hist dead; hbuf region free)
  for (int p = tid; p < K1 * L1; p += 1024) {
    int j = p / L1, k = p - j * L1;
    unsigned long long c = sorted[j];
    int idx = 65535 - (int)(c & 0xFFFFu);
    float sc = tanhf(imono((uint32_t)(c >> 16)) * inv1);
    xsel[p] = xg[(size_t)idx * L1 + k] * sc;
  }
  __syncthreads();
  // RNNCell -> h[328][65-stride]
  for (int p = tid; p < K1 * L2; p += 1024) {
    int row = p >> 6, o = p & 63;
    const float* wr = sWih + o * L1;
    const float* xr = xsel + row * L1;
    float acc = sbih[o];
#pragma unroll
    for (int k = 0; k < L1; ++k) acc += xr[k] * wr[k];
    hbuf[row * 65 + o] = tanhf(acc);
  }
  __syncthreads();

  // pool2: scores -> comp[0..512), counting-rank -> sorted
  for (int j = tid; j < 512; j += 1024) {
    unsigned long long c = 0ULL;
    if (j < K1) {
      const float* hr = hbuf + j * 65;
      float acc = 0.f;
      for (int k = 0; k < L2; ++k) acc += hr[k] * sw2v[k];
      c = ((unsigned long long)mono(acc) << 16) | (unsigned)(65535 - j);
    }
    comp[j] = c;
  }
  __syncthreads();
  if (tid < 512) {
    unsigned long long c = comp[tid];
    int r = 0;
    for (int i = 0; i < 512; i += 8) {
      ulonglong2 v0 = *(const ulonglong2*)&comp[i];
      ulonglong2 v1 = *(const ulonglong2*)&comp[i + 2];
      ulonglong2 v2 = *(const ulonglong2*)&comp[i + 4];
      ulonglong2 v3 = *(const ulonglong2*)&comp[i + 6];
      r += (v0.x > c) + (v0.y > c) + (v1.x > c) + (v1.y > c) +
           (v2.x > c) + (v2.y > c) + (v3.x > c) + (v3.y > c);
    }
    sorted[r] = c;
  }
  __syncthreads();

  // phase G: x2[33][65] = h[sel] * score2
  float* x2f = hbuf + K1 * 65;
  for (int p = tid; p < K2 * L2; p += 1024) {
    int j = p >> 6, k = p & 63;
    unsigned long long c = sorted[j];
    int row = 65535 - (int)(c & 0xFFFFu);
    float sc = tanhf(imono((uint32_t)(c >> 16)) * inv2);
    x2f[j * 65 + k] = hbuf[row * 65 + k] * sc;
  }
  __syncthreads();

  // phase H: y[33][32] = relu(x2 @ W2^T + b2)
  float* yf = x2f + K2 * 65;  // stride 33
  for (int p = tid; p < K2 * L3; p += 1024) {
    int j = p >> 5, o = p & 31;
    const float* xr = x2f + j * 65;
    const float* wr = sW2 + o * 65;
    float acc = sb2[o];
    for (int k = 0; k < L2; ++k) acc += xr[k] * wr[k];
    yf[j * 33 + o] = fmaxf(acc, 0.f);
  }
  __syncthreads();

  // pool3: scores -> comp[0..64), counting-rank(64) -> sorted
  for (int j = tid; j < 64; j += 1024) {
    unsigned long long c = 0ULL;
    if (j < K2) {
      const float* yr = yf + j * 33;
      float acc = 0.f;
      for (int k = 0; k < L3; ++k) acc += yr[k] * sw3v[k];
      c = ((unsigned long long)mono(acc) << 16) | (unsigned)(65535 - j);
    }
    comp[j] = c;
  }
  __syncthreads();
  if (tid < 64) {
    unsigned long long c = comp[tid];
    int r = 0;
    for (int i = 0; i < 64; i += 8) {
      ulonglong2 v0 = *(const ulonglong2*)&comp[i];
      ulonglong2 v1 = *(const ulonglong2*)&comp[i + 2];
      ulonglong2 v2 = *(const ulonglong2*)&comp[i + 4];
      ulonglong2 v3 = *(const ulonglong2*)&comp[i + 6];
      r += (v0.x > c) + (v0.y > c) + (v1.x > c) + (v1.y > c) +
           (v2.x > c) + (v2.y > c) + (v3.x > c) + (v3.y > c);
    }
    sorted[r] = c;
  }
  __syncthreads();

  // phase J: out[4][8] = (y[sel]*score3) @ W3^T + b3
  for (int p = tid; p < K3 * L4; p += 1024) {
    int t = p >> 3, o = p & 7;
    unsigned long long c = sorted[t];
    int row = 65535 - (int)(c & 0xFFFFu);
    float sc = tanhf(imono((uint32_t)(c >> 16)) * inv3);
    const float* yr = yf + row * 33;
    const float* wr = sW3 + o * L3;
    float acc = sb3[o];
    for (int k = 0; k < L3; ++k) acc += yr[k] * sc * wr[k];
    out[((size_t)g * K3 + t) * L4 + o] = acc;
  }
}

extern "C" void kernel_launch(void* const* d_in, const int* in_sizes, int n_in,
                              void* d_out, int out_size, void* d_ws, size_t ws_size,
                              hipStream_t stream) {
  const float* x    = (const float*)d_in[0];
  // d_in[1] = edge_index (unused), d_in[2] = batch (unused: static contiguous grouping)
  const float* w1   = (const float*)d_in[3];
  const float* W_ih = (const float*)d_in[4];
  const float* b_ih = (const float*)d_in[5];
  const float* b_hh = (const float*)d_in[6];
  const float* w2   = (const float*)d_in[7];
  const float* W2   = (const float*)d_in[8];
  const float* b2   = (const float*)d_in[9];
  const float* w3   = (const float*)d_in[10];
  const float* W3   = (const float*)d_in[11];
  const float* b3   = (const float*)d_in[12];
  float* out = (float*)d_out;

  uint16_t* key16 = (uint16_t*)d_ws;                                  // 8 MB
  uint32_t* histg = (uint32_t*)((char*)d_ws + (size_t)NGRAPH * NPG * 2);  // 4 MB

  score_hist_kernel<<<dim3(NGRAPH * SEGS), dim3(1024), 0, stream>>>(
      x, w1, key16, histg);
  select_mlp_kernel<<<dim3(NGRAPH), dim3(1024), 0, stream>>>(
      x, key16, histg, w1, W_ih, b_ih, b_hh, w2, W2, b2, w3, W3, b3, out);
}

// Round 8
// 69.713 us; speedup vs baseline: 1.0914x; 1.0914x over previous
//
#include <hip/hip_runtime.h>
#include <stdint.h>
#include <math.h>

constexpr int NPG = 32768;
constexpr int NGRAPH = 128;
constexpr int L1 = 5, L2 = 64, L3 = 32, L4 = 8;
constexpr int K1 = 328, K2 = 33, K3 = 4;

__device__ __forceinline__ uint32_t mono(float f) {
  uint32_t u = __float_as_uint(f);
  return (u & 0x80000000u) ? ~u : (u | 0x80000000u);
}
__device__ __forceinline__ float imono(uint32_t k) {
  uint32_t u = (k & 0x80000000u) ? (k ^ 0x80000000u) : ~k;
  return __uint_as_float(u);
}

// wave-0: pick threshold bucket from nb-bin histogram (suffix scan from top).
__device__ __forceinline__ void pick_bucket(const uint32_t* hist, int nb, int bits,
                                            uint32_t* s_prefix, int* s_rem,
                                            int* s_nc, int tid) {
  if (tid < 64) {
    const int chunk = (nb >= 64) ? (nb >> 6) : 1;
    const int nlane = (nb >= 64) ? 64 : nb;
    const int base = tid * chunk;
    uint32_t S = 0;
    if (tid < nlane)
      for (int b = 0; b < chunk; ++b) S += hist[base + b];
    uint32_t incl = S;
    for (int d = 1; d < 64; d <<= 1) {
      uint32_t t = __shfl_down(incl, d);
      if (tid + d < 64) incl += t;
    }
    uint32_t above = incl - S;
    uint32_t rem = (uint32_t)*s_rem;
    if (tid < nlane && above < rem && rem <= incl) {  // exactly one winner
      uint32_t cum = above;
      for (int b = chunk - 1; b >= 0; --b) {
        uint32_t h = hist[base + b];
        if (cum + h >= rem) {
          int rnew = (int)(rem - cum);
          *s_rem = rnew;
          *s_nc = (K1 - rnew) + (int)h;
          *s_prefix = (*s_prefix << bits) | (uint32_t)(base + b);
          break;
        }
        cum += h;
      }
    }
  }
}

// ---- kernel 1: DENSE score stream. 2048 blocks x 256 thr, 40 KB LDS ----
// Wave-contiguous float4 loads (16 B/lane dense) -> LDS bounce -> stride-10
// LDS reads (16 even banks, 4-way) -> packed key16 u32 dense store.
__global__ __launch_bounds__(256) void score_kernel(
    const float* __restrict__ x, const float* __restrict__ w1,
    uint32_t* __restrict__ key32) {
  __shared__ __align__(16) float sb[2048 * L1];   // 40 KB
  const int tid = threadIdx.x;
  const int g = blockIdx.x >> 4;
  const int bg = blockIdx.x & 15;
  const float w10 = w1[0], w11 = w1[1], w12 = w1[2], w13 = w1[3], w14 = w1[4];
  const float4* src = (const float4*)(x + ((size_t)g * NPG + bg * 2048) * L1);
#pragma unroll
  for (int k = 0; k < 10; ++k)
    ((float4*)sb)[tid + 256 * k] = src[tid + 256 * k];
  __syncthreads();
  uint32_t* kg = key32 + (size_t)g * (NPG / 2) + bg * 1024;
#pragma unroll
  for (int p = 0; p < 4; ++p) {
    const int np = tid + 256 * p;                 // node pair
    const float* r = sb + np * 10;
    float d0 = r[0]*w10 + r[1]*w11 + r[2]*w12 + r[3]*w13 + r[4]*w14;
    float d1 = r[5]*w10 + r[6]*w11 + r[7]*w12 + r[8]*w13 + r[9]*w14;
    kg[np] = (mono(d0) >> 16) | (mono(d1) & 0xFFFF0000u);   // dense u32 store
  }
}

// ---- kernel 2: per-graph threshold + collect + exact rank + full MLP ----
__global__ __launch_bounds__(1024, 1) void select_mlp_kernel(
    const float* __restrict__ x, const uint16_t* __restrict__ key16,
    const float* __restrict__ w1, const float* __restrict__ W_ih,
    const float* __restrict__ b_ih, const float* __restrict__ b_hh,
    const float* __restrict__ w2, const float* __restrict__ W2,
    const float* __restrict__ b2, const float* __restrict__ w3,
    const float* __restrict__ W3, const float* __restrict__ b3,
    float* __restrict__ out) {
  __shared__ __align__(16) float hbuf[K1 * 65 + K2 * 65 + K2 * 33];  // 98.2 KB
  __shared__ __align__(16) unsigned long long comp[1024];   // 8 KB
  __shared__ __align__(16) unsigned long long sorted[512];  // 4 KB
  __shared__ __align__(16) float fa[4608];                  // 18 KB
  __shared__ uint32_t s_prefix;
  __shared__ int s_rem, s_nc, s_cnt;
  __shared__ float s_inv[3];

  // selection scratch overlaps hbuf (dead before hbuf written):
  uint32_t* whist = (uint32_t*)hbuf;            // [16][264] per-wave hists
  uint32_t* hist256 = (uint32_t*)hbuf + 16 * 264;  // merged 256 bins
  float* xsel = fa;                  // [K1*L1]
  float* sWih = fa + 1640;
  float* sbih = fa + 1960;           // b_ih + b_hh
  float* sW2  = fa + 2024;           // [L3][65]
  float* sb2  = fa + 4104;
  float* sw2v = fa + 4136;
  float* sw3v = fa + 4200;
  float* sW3  = fa + 4232;
  float* sb3  = fa + 4488;

  const int tid = threadIdx.x;
  const int wid = tid >> 6;
  const int g = blockIdx.x;
  const float* xg = x + (size_t)g * NPG * L1;
  const uint16_t* kg = key16 + (size_t)g * NPG;

  for (int i = tid; i < 16 * 264 + 256; i += 1024) ((uint32_t*)hbuf)[i] = 0;
  for (int i = tid; i < L2 * L1; i += 1024) sWih[i] = W_ih[i];
  for (int i = tid; i < L2; i += 1024) { sbih[i] = b_ih[i] + b_hh[i]; sw2v[i] = w2[i]; }
  for (int i = tid; i < L3 * L2; i += 1024) sW2[(i >> 6) * 65 + (i & 63)] = W2[i];
  for (int i = tid; i < L3; i += 1024) { sb2[i] = b2[i]; sw3v[i] = w3[i]; }
  for (int i = tid; i < L4 * L3; i += 1024) sW3[i] = W3[i];
  for (int i = tid; i < L4; i += 1024) sb3[i] = b3[i];
  if (tid == 0) {
    s_cnt = 0; s_rem = K1; s_nc = 0; s_prefix = 0u;
    float s = 0.f;
    for (int k = 0; k < L1; ++k) s += w1[k] * w1[k];
    s_inv[0] = 1.f / sqrtf(s);
  } else if (tid == 1) {
    float s = 0.f;
    for (int k = 0; k < L2; ++k) s += w2[k] * w2[k];
    s_inv[1] = 1.f / sqrtf(s);
  } else if (tid == 2) {
    float s = 0.f;
    for (int k = 0; k < L3; ++k) s += w3[k] * w3[k];
    s_inv[2] = 1.f / sqrtf(s);
  }
  const float w10 = w1[0], w11 = w1[1], w12 = w1[2], w13 = w1[3], w14 = w1[4];
  __syncthreads();

  // per-wave 256-bin histogram of key16>>8 (dense global reads, no cross-wave contention)
  {
    uint32_t* wh = whist + wid * 264;
#pragma unroll
    for (int q = 0; q < 8; ++q) {
      uint2 pk = ((const uint2*)kg)[tid + 1024 * q];
      atomicAdd(&wh[(pk.x >> 8) & 0xFFu], 1u);
      atomicAdd(&wh[(pk.x >> 24)], 1u);
      atomicAdd(&wh[(pk.y >> 8) & 0xFFu], 1u);
      atomicAdd(&wh[(pk.y >> 24)], 1u);
    }
  }
  __syncthreads();
  if (tid < 256) {
    uint32_t s = 0;
#pragma unroll
    for (int w = 0; w < 16; ++w) s += whist[w * 264 + tid];
    hist256[tid] = s;
  }
  __syncthreads();

  // threshold: 8-bit digit, then 8-bit refine if bucket too fat
  pick_bucket(hist256, 256, 8, &s_prefix, &s_rem, &s_nc, tid);
  __syncthreads();
  int consumed = 8;
  if (s_nc > 1024) {
    const uint32_t pref8 = s_prefix;
    __syncthreads();
    if (tid < 256) hist256[tid] = 0;
    __syncthreads();
#pragma unroll
    for (int q = 0; q < 8; ++q) {
      uint2 pk = ((const uint2*)kg)[tid + 1024 * q];
      uint32_t h0 = pk.x & 0xFFFFu, h1 = pk.x >> 16;
      uint32_t h2 = pk.y & 0xFFFFu, h3 = pk.y >> 16;
      if ((h0 >> 8) == pref8) atomicAdd(&hist256[h0 & 255u], 1u);
      if ((h1 >> 8) == pref8) atomicAdd(&hist256[h1 & 255u], 1u);
      if ((h2 >> 8) == pref8) atomicAdd(&hist256[h2 & 255u], 1u);
      if ((h3 >> 8) == pref8) atomicAdd(&hist256[h3 & 255u], 1u);
    }
    __syncthreads();
    pick_bucket(hist256, 256, 8, &s_prefix, &s_rem, &s_nc, tid);
    __syncthreads();
    consumed = 16;
  }
  const uint32_t T16 = s_prefix << (16 - consumed);  // monotone-trunc superset threshold

  // collect candidates; recompute EXACT dot for each
  for (int q = 0; q < 8; ++q) {
    const int g4 = tid + 1024 * q;
    uint2 pk = ((const uint2*)kg)[g4];
    uint32_t h[4] = { pk.x & 0xFFFFu, pk.x >> 16, pk.y & 0xFFFFu, pk.y >> 16 };
#pragma unroll
    for (int j = 0; j < 4; ++j) {
      if (h[j] >= T16) {
        int p = atomicAdd(&s_cnt, 1);
        if (p < 1024) {
          int i = 4 * g4 + j;
          const float* r = xg + (size_t)i * L1;
          float dv = r[0]*w10 + r[1]*w11 + r[2]*w12 + r[3]*w13 + r[4]*w14;
          comp[p] = ((unsigned long long)mono(dv) << 16) | (unsigned)(65535 - i);
        }
      }
    }
  }
  __syncthreads();
  int cnt = s_cnt; if (cnt > 1024) cnt = 1024;
  const int nrk = (cnt <= 512) ? 512 : 1024;
  for (int i = tid; i < nrk; i += 1024)
    if (i >= cnt) comp[i] = 0ULL;
  __syncthreads();
  if (tid < nrk) {   // unrolled broadcast counting-rank
    unsigned long long c = comp[tid];
    int r = 0;
    for (int i = 0; i < nrk; i += 8) {
      ulonglong2 v0 = *(const ulonglong2*)&comp[i];
      ulonglong2 v1 = *(const ulonglong2*)&comp[i + 2];
      ulonglong2 v2 = *(const ulonglong2*)&comp[i + 4];
      ulonglong2 v3 = *(const ulonglong2*)&comp[i + 6];
      r += (v0.x > c) + (v0.y > c) + (v1.x > c) + (v1.y > c) +
           (v2.x > c) + (v2.y > c) + (v3.x > c) + (v3.y > c);
    }
    if (r < K1) sorted[r] = c;
  }
  __syncthreads();

  const float inv1 = s_inv[0], inv2 = s_inv[1], inv3 = s_inv[2];

  // phase E: gather x rows * score1 (selection scratch dead; hbuf free)
  for (int p = tid; p < K1 * L1; p += 1024) {
    int j = p / L1, k = p - j * L1;
    unsigned long long c = sorted[j];
    int idx = 65535 - (int)(c & 0xFFFFu);
    float sc = tanhf(imono((uint32_t)(c >> 16)) * inv1);
    xsel[p] = xg[(size_t)idx * L1 + k] * sc;
  }
  __syncthreads();
  // RNNCell -> h[328][65-stride]
  for (int p = tid; p < K1 * L2; p += 1024) {
    int row = p >> 6, o = p & 63;
    const float* wr = sWih + o * L1;
    const float* xr = xsel + row * L1;
    float acc = sbih[o];
#pragma unroll
    for (int k = 0; k < L1; ++k) acc += xr[k] * wr[k];
    hbuf[row * 65 + o] = tanhf(acc);
  }
  __syncthreads();

  // pool2: scores -> comp[0..512), counting-rank -> sorted
  for (int j = tid; j < 512; j += 1024) {
    unsigned long long c = 0ULL;
    if (j < K1) {
      const float* hr = hbuf + j * 65;
      float acc = 0.f;
      for (int k = 0; k < L2; ++k) acc += hr[k] * sw2v[k];
      c = ((unsigned long long)mono(acc) << 16) | (unsigned)(65535 - j);
    }
    comp[j] = c;
  }
  __syncthreads();
  if (tid < 512) {
    unsigned long long c = comp[tid];
    int r = 0;
    for (int i = 0; i < 512; i += 8) {
      ulonglong2 v0 = *(const ulonglong2*)&comp[i];
      ulonglong2 v1 = *(const ulonglong2*)&comp[i + 2];
      ulonglong2 v2 = *(const ulonglong2*)&comp[i + 4];
      ulonglong2 v3 = *(const ulonglong2*)&comp[i + 6];
      r += (v0.x > c) + (v0.y > c) + (v1.x > c) + (v1.y > c) +
           (v2.x > c) + (v2.y > c) + (v3.x > c) + (v3.y > c);
    }
    sorted[r] = c;
  }
  __syncthreads();

  // phase G: x2[33][65] = h[sel] * score2
  float* x2f = hbuf + K1 * 65;
  for (int p = tid; p < K2 * L2; p += 1024) {
    int j = p >> 6, k = p & 63;
    unsigned long long c = sorted[j];
    int row = 65535 - (int)(c & 0xFFFFu);
    float sc = tanhf(imono((uint32_t)(c >> 16)) * inv2);
    x2f[j * 65 + k] = hbuf[row * 65 + k] * sc;
  }
  __syncthreads();

  // phase H: y[33][32] = relu(x2 @ W2^T + b2)
  float* yf = x2f + K2 * 65;  // stride 33
  for (int p = tid; p < K2 * L3; p += 1024) {
    int j = p >> 5, o = p & 31;
    const float* xr = x2f + j * 65;
    const float* wr = sW2 + o * 65;
    float acc = sb2[o];
    for (int k = 0; k < L2; ++k) acc += xr[k] * wr[k];
    yf[j * 33 + o] = fmaxf(acc, 0.f);
  }
  __syncthreads();

  // pool3: scores -> comp[0..64), counting-rank(64) -> sorted
  for (int j = tid; j < 64; j += 1024) {
    unsigned long long c = 0ULL;
    if (j < K2) {
      const float* yr = yf + j * 33;
      float acc = 0.f;
      for (int k = 0; k < L3; ++k) acc += yr[k] * sw3v[k];
      c = ((unsigned long long)mono(acc) << 16) | (unsigned)(65535 - j);
    }
    comp[j] = c;
  }
  __syncthreads();
  if (tid < 64) {
    unsigned long long c = comp[tid];
    int r = 0;
    for (int i = 0; i < 64; i += 8) {
      ulonglong2 v0 = *(const ulonglong2*)&comp[i];
      ulonglong2 v1 = *(const ulonglong2*)&comp[i + 2];
      ulonglong2 v2 = *(const ulonglong2*)&comp[i + 4];
      ulonglong2 v3 = *(const ulonglong2*)&comp[i + 6];
      r += (v0.x > c) + (v0.y > c) + (v1.x > c) + (v1.y > c) +
           (v2.x > c) + (v2.y > c) + (v3.x > c) + (v3.y > c);
    }
    sorted[r] = c;
  }
  __syncthreads();

  // phase J: out[4][8] = (y[sel]*score3) @ W3^T + b3
  for (int p = tid; p < K3 * L4; p += 1024) {
    int t = p >> 3, o = p & 7;
    unsigned long long c = sorted[t];
    int row = 65535 - (int)(c & 0xFFFFu);
    float sc = tanhf(imono((uint32_t)(c >> 16)) * inv3);
    const float* yr = yf + row * 33;
    const float* wr = sW3 + o * L3;
    float acc = sb3[o];
    for (int k = 0; k < L3; ++k) acc += yr[k] * sc * wr[k];
    out[((size_t)g * K3 + t) * L4 + o] = acc;
  }
}

extern "C" void kernel_launch(void* const* d_in, const int* in_sizes, int n_in,
                              void* d_out, int out_size, void* d_ws, size_t ws_size,
                              hipStream_t stream) {
  const float* x    = (const float*)d_in[0];
  // d_in[1] = edge_index (unused), d_in[2] = batch (unused: static contiguous grouping)
  const float* w1   = (const float*)d_in[3];
  const float* W_ih = (const float*)d_in[4];
  const float* b_ih = (const float*)d_in[5];
  const float* b_hh = (const float*)d_in[6];
  const float* w2   = (const float*)d_in[7];
  const float* W2   = (const float*)d_in[8];
  const float* b2   = (const float*)d_in[9];
  const float* w3   = (const float*)d_in[10];
  const float* W3   = (const float*)d_in[11];
  const float* b3   = (const float*)d_in[12];
  float* out = (float*)d_out;

  uint32_t* key32 = (uint32_t*)d_ws;   // 8 MB packed key16

  score_kernel<<<dim3(NGRAPH * 16), dim3(256), 0, stream>>>(x, w1, key32);
  select_mlp_kernel<<<dim3(NGRAPH), dim3(1024), 0, stream>>>(
      x, (const uint16_t*)key32, w1, W_ih, b_ih, b_hh, w2, W2, b2, w3, W3, b3, out);
}